// Round 10
// baseline (104.714 us; speedup 1.0000x reference)
//
#include <hip/hip_runtime.h>
#include <hip/hip_fp16.h>
#include <math.h>

// ---- geometry constants (match reference) ----
constexpr int   VIEWS = 128;
constexpr int   NDET  = 512;
constexpr int   IMG   = 256;
constexpr int   BATCH = 2;
constexpr float SID_F = 750.0f;
constexpr float SDD_F = 1250.0f;
constexpr float DET_ELT = 1.2f;
constexpr float DET_OFF = 0.0f;
constexpr float STEP  = 1.0f;
constexpr int   NS = 364;                       // ceil(2R)+1, R = 128*sqrt(2)
constexpr float T0 = (float)(750.0 - 181.01933598375618);  // SID - R

// ---- vertical-pair LDS texture, processed in two bands ----
// Entry (p, j) packs fp16 pixels of tile rows (p, p+1) at tile col j
// (tile row = image row + 2, tile col = image col + 2; border = 0).
// Sample (ip, jp): ONE ds_read2_b32 of entries (ip,jp),(ip,jp+1):
//   lo dword = (top-left, bot-left), hi = (top-right, bot-right).
constexpr int COLS  = 260;                      // j in [0,259]; reads jp,jp+1, jp<=258
constexpr int CSTR  = 261;                      // odd stride: bank spread
constexpr int SPLIT = 130;                      // band boundary in tile-row coords
constexpr int NE_T  = 131;                      // top band: entries 0..130 (+1 guard)
constexpr int NE_B  = 130;                      // bottom: entries 129..258 (-1 guard)
constexpr int BLO_B = 129;

typedef _Float16 h2 __attribute__((ext_vector_type(2)));
using v2h = decltype(__builtin_amdgcn_cvt_pkrtz(0.0f, 0.0f));

__device__ __forceinline__ float band_loop(const unsigned* __restrict__ tb,
                                           int lo, int hi, int chunk,
                                           float dx, float ndy,
                                           float cx3, float cy3) {
    float acc = 0.0f;
    const int start = lo + chunk;
    // exact count: d>=0 -> d/2+1; any d<0 -> 0 (round-8 lesson)
    const int iters = max(0, (hi - start + 2) / 2);
    float sfv = (float)start;
#pragma unroll 4
    for (int k = 0; k < iters; ++k) {
        const float jx2 = fmaf(sfv, dx, cx3);
        const float iy2 = fmaf(sfv, ndy, cy3);
        sfv += 2.0f;                            // exact (integer-valued floats)
        const int jp = (int)jx2;                // trunc == floor (positive)
        const int ip = (int)iy2;
        const float fj = jx2 - (float)jp;
        const float fi = iy2 - (float)ip;
        const int addr = ip * CSTR + jp;        // tb pre-biased per band
        const unsigned Lu = tb[addr];           // (t0, b0)
        const unsigned Hu = tb[addr + 1];       // (t1, b1)  -> ds_read2_b32
        const h2 L = __builtin_bit_cast(h2, Lu);
        const h2 H = __builtin_bit_cast(h2, Hu);
        const h2 fj2 = __builtin_bit_cast(h2, __builtin_amdgcn_cvt_pkrtz(fj, fj));
        const h2 r = fj2 * (H - L) + L;         // v_pk_fma: (top, bot)
#if __has_builtin(__builtin_amdgcn_fdot2)
        const h2 wv = __builtin_bit_cast(h2, __builtin_amdgcn_cvt_pkrtz(1.0f - fi, fi));
        acc = __builtin_amdgcn_fdot2(__builtin_bit_cast(v2h, r),
                                     __builtin_bit_cast(v2h, wv), acc, false);
#else
        acc = fmaf(fi, (float)r.y - (float)r.x, acc + (float)r.x);
#endif
    }
    return acc;
}

// Block = one (b, view): 1024 threads = 512 detectors x 2 t-chunks.
__global__ __launch_bounds__(1024) void fanbeam_pair(const float* __restrict__ img,
                                                     float* __restrict__ out) {
    __shared__ unsigned tile[NE_T * CSTR];      // 34191 dwords = 136,764 B
    __shared__ float red[1024];
    const int tid = threadIdx.x;
    const int blk = blockIdx.x;                 // = b*VIEWS + v
    const int v = blk & (VIEWS - 1);
    const int b = blk >> 7;
    const float* __restrict__ src = img + b * IMG * IMG;

    // ---- per-ray geometry (float path identical to passing round-9) ----
    const int n     = tid & (NDET - 1);
    const int chunk = tid >> 9;
    const float beta = (float)((double)v * 0.049087385212340517);  // v * pi/64
    const float cb = cosf(beta);
    const float sb = sinf(beta);
    const float u  = ((float)n - 255.5f) * DET_ELT + DET_OFF;
    float dx = fmaf(-u, sb, -SDD_F * cb);
    float dy = fmaf( u, cb, -SDD_F * sb);
    const float rinv = rsqrtf(fmaf(dx, dx, dy * dy));
    dx *= rinv;
    dy *= rinv;
    const float ndy = -dy;
    const float sx = SID_F * cb;
    const float sy = SID_F * sb;
    const float cx3 = fmaf(T0, dx,  sx + 127.5f + 2.0f);   // jx2 = sf*dx + cx3
    const float cy3 = fmaf(T0, ndy, 127.5f - sy + 2.0f);   // iy2 = sf*ndy + cy3

    // slab: |px|,|py| <= 128.75 -> jp,ip in [0,258], no per-sample clamps
    const float invx = 1.0f / dx;
    const float invy = 1.0f / dy;
    const float ta = (-128.75f - sx) * invx, tb2 = (128.75f - sx) * invx;
    const float tc = (-128.75f - sy) * invy, td = (128.75f - sy) * invy;
    const float tmin = fmaxf(fmaxf(fminf(ta, tb2), fminf(tc, td)), T0);
    const float tmax = fminf(fminf(fmaxf(ta, tb2), fmaxf(tc, td)), T0 + (float)(NS - 1));
    int slo = (int)ceilf(tmin - T0);
    int shi = (int)floorf(tmax - T0);
    slo = max(slo, 0);
    shi = min(shi, NS - 1);

    // band crossing: iy2(s) == SPLIT at s = zf = (cy3-130)/dy  (last op is mul:
    // no fp-contract ambiguity). +-1-entry staging guard absorbs float fuzz.
    float zf = (cy3 - (float)SPLIT) * invy;
    zf = fminf(fmaxf(zf, -1.0e6f), 1.0e6f);    // clamp inf/NaN before int cvt
    const int zc  = (int)ceilf(zf);
    const int zfl = (int)floorf(zf);

    // ---- phase T: stage top band (entries 0..130), process iy2 < 130 ----
    for (int k = tid; k < NE_T * COLS; k += 1024) {
        const int e = k / COLS;
        const int j = k - e * COLS;
        const int r0 = e - 2, r1 = e - 1, c = j - 2;   // image coords
        const bool cv = (unsigned)c < 256u;
        unsigned plo = 0, phi = 0;
        if (cv && (unsigned)r0 < 256u)
            plo = __half_as_ushort(__float2half(src[(r0 << 8) + c]));
        if (cv && (unsigned)r1 < 256u)
            phi = __half_as_ushort(__float2half(src[(r1 << 8) + c]));
        tile[e * CSTR + j] = plo | (phi << 16);
    }
    __syncthreads();
    int lo_, hi_;
    if (ndy > 0.0f)      { lo_ = slo; hi_ = min(shi, zc - 1); }
    else if (ndy < 0.0f) { lo_ = max(slo, zfl + 1); hi_ = shi; }
    else                 { lo_ = (cy3 < (float)SPLIT) ? slo : 1;
                           hi_ = (cy3 < (float)SPLIT) ? shi : 0; }
    const float accT = band_loop(tile, lo_, hi_, chunk, dx, ndy, cx3, cy3);
    __syncthreads();                            // all reads done before restage

    // ---- phase B: restage bottom band (entries 129..258), process iy2 >= 130 ----
    for (int k = tid; k < NE_B * COLS; k += 1024) {
        const int e = k / COLS;
        const int j = k - e * COLS;
        const int p = e + BLO_B;                // 129..258
        const int r0 = p - 2, r1 = p - 1, c = j - 2;
        const bool cv = (unsigned)c < 256u;
        unsigned plo = 0, phi = 0;
        if (cv && (unsigned)r0 < 256u)
            plo = __half_as_ushort(__float2half(src[(r0 << 8) + c]));
        if (cv && (unsigned)r1 < 256u)
            phi = __half_as_ushort(__float2half(src[(r1 << 8) + c]));
        tile[e * CSTR + j] = plo | (phi << 16);
    }
    __syncthreads();
    if (ndy > 0.0f)      { lo_ = max(slo, zc); hi_ = shi; }
    else if (ndy < 0.0f) { lo_ = slo; hi_ = min(shi, zfl); }
    else                 { lo_ = (cy3 < (float)SPLIT) ? 1 : slo;
                           hi_ = (cy3 < (float)SPLIT) ? 0 : shi; }
    const float accB = band_loop(tile - BLO_B * CSTR, lo_, hi_, chunk,
                                 dx, ndy, cx3, cy3);

    // ---- reduce the 2 t-chunks, write ----
    red[tid] = accT + accB;
    __syncthreads();
    if (tid < 512) {
        out[blk * 512 + tid] = (red[tid] + red[tid + 512]) * STEP;
    }
}

extern "C" void kernel_launch(void* const* d_in, const int* in_sizes, int n_in,
                              void* d_out, int out_size, void* d_ws, size_t ws_size,
                              hipStream_t stream) {
    const float* x = (const float*)d_in[0];
    float* out = (float*)d_out;
    fanbeam_pair<<<BATCH * VIEWS, 1024, 0, stream>>>(x, out);
}

// Round 12
// 81.473 us; speedup vs baseline: 1.2852x; 1.2852x over previous
//
#include <hip/hip_runtime.h>
#include <hip/hip_fp16.h>
#include <math.h>

// ---- geometry constants (match reference) ----
constexpr int   VIEWS = 128;
constexpr int   NDET  = 512;
constexpr int   IMG   = 256;
constexpr int   BATCH = 2;
constexpr float SID_F = 750.0f;
constexpr float SDD_F = 1250.0f;
constexpr float DET_ELT = 1.2f;
constexpr float DET_OFF = 0.0f;
constexpr float STEP  = 1.0f;
constexpr int   NS = 364;                       // ceil(2R)+1, R = 128*sqrt(2)
constexpr float T0 = (float)(750.0 - 181.01933598375618);  // SID - R

// ---- vertical-pair fp16 LDS texture, one BAND per block ----
// Entry (p, j) packs fp16 pixels of tile rows (p, p+1) at tile col j
// (tile row = image row + 2, tile col = image col + 2; border = 0).
// Sample (ip, jp): ONE ds_read2_b32 of entries (ip,jp),(ip,jp+1).
// Band T = entries p 0..130 (owns iy2 < 130, +1 guard);
// Band B = entries p 129..258 (owns iy2 >= 130, -1 guard).
constexpr int CSTR   = 261;                     // entry stride (261 mod 32 = 5)
constexpr int NE_T   = 131;
constexpr int NE_B   = 130;
constexpr int BLO_B  = 129;
constexpr int SPLIT  = 130;
constexpr int TILE_DW = 34192;                  // 131*261=34191, +1 pad for uint4 fill

typedef _Float16 h2 __attribute__((ext_vector_type(2)));
using v2h = decltype(__builtin_amdgcn_cvt_pkrtz(0.0f, 0.0f));

__device__ __forceinline__ unsigned pk16(float lo, float hi) {
    return __builtin_bit_cast(unsigned, __builtin_amdgcn_cvt_pkrtz(lo, hi));
}

// Verbatim round-10 inner loop (correctness-proven: absmax 1.0).
__device__ __forceinline__ float band_loop(const unsigned* __restrict__ tb,
                                           int lo, int hi, int chunk,
                                           float dx, float ndy,
                                           float cx3, float cy3) {
    float acc = 0.0f;
    const int start = lo + chunk;
    const int iters = max(0, (hi - start + 2) / 2);   // exact; 0 for any empty span
    float sfv = (float)start;
#pragma unroll 4
    for (int k = 0; k < iters; ++k) {
        const float jx2 = fmaf(sfv, dx, cx3);
        const float iy2 = fmaf(sfv, ndy, cy3);
        sfv += 2.0f;                            // exact (integer-valued floats)
        const int jp = (int)jx2;                // trunc == floor (positive)
        const int ip = (int)iy2;
        const float fj = jx2 - (float)jp;
        const float fi = iy2 - (float)ip;
        const int addr = ip * CSTR + jp;
        const unsigned Lu = tb[addr];           // (t0, b0)
        const unsigned Hu = tb[addr + 1];       // (t1, b1)  -> one ds_read2_b32
        const h2 L = __builtin_bit_cast(h2, Lu);
        const h2 H = __builtin_bit_cast(h2, Hu);
        const h2 fj2 = __builtin_bit_cast(h2, __builtin_amdgcn_cvt_pkrtz(fj, fj));
        const h2 r = fj2 * (H - L) + L;         // v_pk_fma: (top, bot)
#if __has_builtin(__builtin_amdgcn_fdot2)
        const h2 wv = __builtin_bit_cast(h2, __builtin_amdgcn_cvt_pkrtz(1.0f - fi, fi));
        acc = __builtin_amdgcn_fdot2(__builtin_bit_cast(v2h, r),
                                     __builtin_bit_cast(v2h, wv), acc, false);
#else
        acc = fmaf(fi, (float)r.y - (float)r.x, acc + (float)r.x);
#endif
    }
    return acc;
}

// Block = one (b, view, band): 1024 threads = 512 detectors x 2 t-chunks.
// Bands are INDEPENDENT blocks (no restage barrier); partials combined by
// atomicAdd into memset-zeroed d_out.
__global__ __launch_bounds__(1024) void fanbeam_band(const float* __restrict__ img,
                                                     float* __restrict__ out) {
    __shared__ __align__(16) unsigned tile[TILE_DW];
    __shared__ float red[1024];
    const int tid  = threadIdx.x;
    const int bb   = blockIdx.x;
    const int band = bb & 1;                    // 0 = T, 1 = B
    const int bv   = bb >> 1;                   // = b*VIEWS + v
    const int v = bv & (VIEWS - 1);
    const int b = bv >> 7;
    const float* __restrict__ src = img + b * IMG * IMG;
    const bool bandT = (band == 0);

    // ---- zero-fill tile (uint4), then overwrite interior ----
    for (int k = tid; k < TILE_DW / 4; k += 1024)
        reinterpret_cast<uint4*>(tile)[k] = uint4{0u, 0u, 0u, 0u};
    __syncthreads();

    // full entries: T: e in [2,130] (rows e-2,e-1); B: e in [0,127] (rows e+127,e+128)
    const int NF = bandT ? 129 : 128;
    const int E0 = bandT ? 2 : 0;
    const int R0 = bandT ? 0 : 127;
    for (int k = tid; k < NF * 64; k += 1024) { // 64 quads of 4 cols per entry-row
        const int er = k >> 6;
        const int c  = (k & 63) << 2;           // image col, 16B aligned
        const int e  = E0 + er;
        const int r0 = R0 + er;
        const float4 a = *reinterpret_cast<const float4*>(src + (r0 << 8) + c);
        const float4 d = *reinterpret_cast<const float4*>(src + ((r0 + 1) << 8) + c);
        const int base = e * CSTR + c + 2;
        tile[base + 0] = pk16(a.x, d.x);
        tile[base + 1] = pk16(a.y, d.y);
        tile[base + 2] = pk16(a.z, d.z);
        tile[base + 3] = pk16(a.w, d.w);
    }
    // partial entry row: T e=1 = (row -1, row 0) -> hi only; B e=128 (p=257) =
    // (row 255, row 256) -> lo only. (T e=0, B e=129 stay zero.)
    for (int k = tid; k < 256; k += 1024) {
        if (bandT) {
            const unsigned hb = (unsigned)__half_as_ushort(__float2half(src[k]));
            tile[1 * CSTR + k + 2] = hb << 16;
        } else {
            const unsigned lb = (unsigned)__half_as_ushort(__float2half(src[(255 << 8) + k]));
            tile[128 * CSTR + k + 2] = lb;
        }
    }
    __syncthreads();

    // ---- per-ray geometry (identical float path to passing rounds 9/10) ----
    const int n     = tid & (NDET - 1);
    const int chunk = tid >> 9;
    const float beta = (float)((double)v * 0.049087385212340517);  // v * pi/64
    const float cb = cosf(beta);
    const float sb = sinf(beta);
    const float u  = ((float)n - 255.5f) * DET_ELT + DET_OFF;
    float dx = fmaf(-u, sb, -SDD_F * cb);
    float dy = fmaf( u, cb, -SDD_F * sb);
    const float rinv = rsqrtf(fmaf(dx, dx, dy * dy));
    dx *= rinv;
    dy *= rinv;
    const float ndy = -dy;
    const float sx = SID_F * cb;
    const float sy = SID_F * sb;
    const float cx3 = fmaf(T0, dx,  sx + 127.5f + 2.0f);   // jx2 = sf*dx + cx3
    const float cy3 = fmaf(T0, ndy, 127.5f - sy + 2.0f);   // iy2 = sf*ndy + cy3

    // slab: |px|,|py| <= 128.75 -> jp in [0,258], iy2 in [0.75,258.25]
    const float invx = 1.0f / dx;
    const float invy = 1.0f / dy;
    const float ta = (-128.75f - sx) * invx, tb2 = (128.75f - sx) * invx;
    const float tc = (-128.75f - sy) * invy, td = (128.75f - sy) * invy;
    const float tmin = fmaxf(fmaxf(fminf(ta, tb2), fminf(tc, td)), T0);
    const float tmax = fminf(fminf(fmaxf(ta, tb2), fmaxf(tc, td)), T0 + (float)(NS - 1));
    int slo = (int)ceilf(tmin - T0);
    int shi = (int)floorf(tmax - T0);
    slo = max(slo, 0);
    shi = min(shi, NS - 1);

    // band crossing iy2(s) == 130 at s = zf (round-10 verbatim, proven)
    float zf = (cy3 - (float)SPLIT) * invy;
    zf = fminf(fmaxf(zf, -1.0e6f), 1.0e6f);
    const int zc  = (int)ceilf(zf);
    const int zfl = (int)floorf(zf);

    int lo_, hi_;
    if (bandT) {
        if (ndy > 0.0f)      { lo_ = slo; hi_ = min(shi, zc - 1); }
        else if (ndy < 0.0f) { lo_ = max(slo, zfl + 1); hi_ = shi; }
        else                 { lo_ = (cy3 < (float)SPLIT) ? slo : 1;
                               hi_ = (cy3 < (float)SPLIT) ? shi : 0; }
    } else {
        if (ndy > 0.0f)      { lo_ = max(slo, zc); hi_ = shi; }
        else if (ndy < 0.0f) { lo_ = slo; hi_ = min(shi, zfl); }
        else                 { lo_ = (cy3 < (float)SPLIT) ? 1 : slo;
                               hi_ = (cy3 < (float)SPLIT) ? 0 : shi; }
    }
    // Band B uses LOCAL row coords: iy2_loc = iy2 - 129 (entry p = 129 + ip_loc).
    const float cy3loc = bandT ? cy3 : (cy3 - (float)BLO_B);
    const float acc = band_loop(tile, lo_, hi_, chunk, dx, ndy, cx3, cy3loc);

    // ---- reduce 2 t-chunks, atomically combine bands ----
    red[tid] = acc;
    __syncthreads();
    if (tid < 512) {
        const float r = (red[tid] + red[tid + 512]) * STEP;
        unsafeAtomicAdd(&out[bv * 512 + tid], r);
    }
}

extern "C" void kernel_launch(void* const* d_in, const int* in_sizes, int n_in,
                              void* d_out, int out_size, void* d_ws, size_t ws_size,
                              hipStream_t stream) {
    const float* x = (const float*)d_in[0];
    float* out = (float*)d_out;
    hipMemsetAsync(out, 0, (size_t)out_size * sizeof(float), stream);
    fanbeam_band<<<2 * BATCH * VIEWS, 1024, 0, stream>>>(x, out);
}

// Round 13
// 80.066 us; speedup vs baseline: 1.3078x; 1.0176x over previous
//
#include <hip/hip_runtime.h>
#include <hip/hip_fp16.h>
#include <math.h>

// ---- geometry constants (match reference) ----
constexpr int   VIEWS = 128;
constexpr int   NDET  = 512;
constexpr int   IMG   = 256;
constexpr int   BATCH = 2;
constexpr float SID_F = 750.0f;
constexpr float SDD_F = 1250.0f;
constexpr float DET_ELT = 1.2f;
constexpr float DET_OFF = 0.0f;
constexpr float STEP  = 1.0f;
constexpr int   NS = 364;                       // ceil(2R)+1, R = 128*sqrt(2)
constexpr float T0 = (float)(750.0 - 181.01933598375618);  // SID - R

// ---- flat fp16 HALF-BAND texture (round-9 layout, halved rows) ----
// Tile coords: image pixel (i,j) lives at tile row i+2, tile half-col j+2;
// row stride 262 halfs = 131 dwords (odd -> bank spread). Border = 0.
// Band T = tile rows 0..131 (owns iy2 < 130; row 131 = img 129 is a REAL-data
// guard row). Band B = tile rows 129..259 stored at local rows 0..130
// (owns iy2 >= 130; local 0 = img 127 real-data guard; local 129,130 zero).
constexpr int TWSTR   = 131;                    // dwords per tile row
constexpr int TILE_DW = 132 * TWSTR;            // 17292 dw = 69,168 B (x4-divisible)
constexpr int SPLIT   = 130;                    // band boundary, tile-row coords
constexpr int BLO_B   = 129;                    // band B tile-row origin

typedef _Float16 h2 __attribute__((ext_vector_type(2)));
using v2h = decltype(__builtin_amdgcn_cvt_pkrtz(0.0f, 0.0f));

__device__ __forceinline__ unsigned pk16(float lo, float hi) {
    return __builtin_bit_cast(unsigned, __builtin_amdgcn_cvt_pkrtz(lo, hi));
}

// VERBATIM round-9 inner loop (correctness-proven: absmax 1.0).
__device__ __forceinline__ float band_loop(const unsigned* __restrict__ tile32,
                                           int lo, int hi, int chunk,
                                           float dx, float ndy,
                                           float cx3, float cy3) {
    float acc = 0.0f;
    const int start = lo + chunk;
    const int iters = max(0, (hi - start + 2) / 2);   // exact; 0 for any empty span
    float sfv = (float)start;
#pragma unroll 4
    for (int k = 0; k < iters; ++k) {
        const float jx2 = fmaf(sfv, dx, cx3);
        const float iy2 = fmaf(sfv, ndy, cy3);
        sfv += 2.0f;                            // exact (integer-valued floats)
        const int jp = (int)jx2;                // trunc == floor (positive)
        const int ip = (int)iy2;
        const float fj = jx2 - (float)jp;
        const float fi = iy2 - (float)ip;
        const int w = ip * TWSTR + (jp >> 1);
        const unsigned w0 = tile32[w];
        const unsigned w1 = tile32[w + 1];
        const unsigned w2 = tile32[w + TWSTR];
        const unsigned w3 = tile32[w + TWSTR + 1];
        const unsigned sh = (unsigned)jp << 4;  // alignbit uses shift[4:0]
        const unsigned ptop = __builtin_amdgcn_alignbit(w1, w0, sh);  // (t0,t1)
        const unsigned pbot = __builtin_amdgcn_alignbit(w3, w2, sh);  // (b0,b1)
        const unsigned Lu = __builtin_amdgcn_perm(pbot, ptop, 0x05040100u);
        const unsigned Hu = __builtin_amdgcn_perm(pbot, ptop, 0x07060302u);
        const h2 L = __builtin_bit_cast(h2, Lu);
        const h2 H = __builtin_bit_cast(h2, Hu);
        const h2 fj2 = __builtin_bit_cast(h2, __builtin_amdgcn_cvt_pkrtz(fj, fj));
        const h2 r = fj2 * (H - L) + L;         // v_pk_fma: (top, bot)
#if __has_builtin(__builtin_amdgcn_fdot2)
        const h2 wv = __builtin_bit_cast(h2, __builtin_amdgcn_cvt_pkrtz(1.0f - fi, fi));
        acc = __builtin_amdgcn_fdot2(__builtin_bit_cast(v2h, r),
                                     __builtin_bit_cast(v2h, wv), acc, false);
#else
        acc = fmaf(fi, (float)r.y - (float)r.x, acc + (float)r.x);
#endif
    }
    return acc;
}

// Block = one (b, view, band): 1024 threads = 512 detectors x 2 t-chunks.
// 73.3 KB LDS -> 2 blocks/CU co-resident (32 waves/CU): band/ray load
// imbalance is absorbed across blocks. Partials combined by atomicAdd.
__global__ __launch_bounds__(1024) void fanbeam_band2(const float* __restrict__ img,
                                                      float* __restrict__ out) {
    __shared__ __align__(16) unsigned tile[TILE_DW];
    __shared__ float red[1024];
    const int tid  = threadIdx.x;
    const int bb   = blockIdx.x;
    const int band = bb & 1;                    // 0 = T, 1 = B
    const int bv   = bb >> 1;                   // = b*VIEWS + v
    const int v = bv & (VIEWS - 1);
    const int b = bv >> 7;
    const float* __restrict__ src = img + b * IMG * IMG;
    const bool bandT = (band == 0);

    // ---- zero-fill tile (uint4) ----
    for (int k = tid; k < TILE_DW / 4; k += 1024)
        reinterpret_cast<uint4*>(tile)[k] = uint4{0u, 0u, 0u, 0u};
    __syncthreads();

    // ---- stage band interior as fp16 (float4 loads, 2 pk16 dwords per quad) ----
    // T: tile rows 2..131 = img rows 0..129 (130 rows).
    // B: local rows 0..128 = img rows 127..255 (129 rows).
    const int NR = bandT ? 130 : 129;
    const int RT = bandT ? 2 : 0;               // local tile-row of first staged row
    const int RI = bandT ? 0 : 127;             // image row of first staged row
    for (int k = tid; k < NR * 64; k += 1024) { // 64 col-quads per row
        const int er = k >> 6;
        const int c  = (k & 63) << 2;           // image col, 16B aligned
        const float4 a = *reinterpret_cast<const float4*>(src + ((RI + er) << 8) + c);
        const int base = (RT + er) * TWSTR + (c >> 1) + 1;  // half-col c+2
        tile[base]     = pk16(a.x, a.y);
        tile[base + 1] = pk16(a.z, a.w);
    }
    __syncthreads();

    // ---- per-ray geometry (identical float path to passing rounds 9/12) ----
    const int n     = tid & (NDET - 1);
    const int chunk = tid >> 9;
    const float beta = (float)((double)v * 0.049087385212340517);  // v * pi/64
    const float cb = cosf(beta);
    const float sb = sinf(beta);
    const float u  = ((float)n - 255.5f) * DET_ELT + DET_OFF;
    float dx = fmaf(-u, sb, -SDD_F * cb);
    float dy = fmaf( u, cb, -SDD_F * sb);
    const float rinv = rsqrtf(fmaf(dx, dx, dy * dy));
    dx *= rinv;
    dy *= rinv;
    const float ndy = -dy;
    const float sx = SID_F * cb;
    const float sy = SID_F * sb;
    const float cx3 = fmaf(T0, dx,  sx + 127.5f + 2.0f);   // jx2 = sf*dx + cx3
    const float cy3 = fmaf(T0, ndy, 127.5f - sy + 2.0f);   // iy2 = sf*ndy + cy3

    // slab: |px|,|py| <= 128.75 -> jp,ip in [0,258], no per-sample clamps
    const float invx = 1.0f / dx;
    const float invy = 1.0f / dy;
    const float ta = (-128.75f - sx) * invx, tb2 = (128.75f - sx) * invx;
    const float tc = (-128.75f - sy) * invy, td = (128.75f - sy) * invy;
    const float tmin = fmaxf(fmaxf(fminf(ta, tb2), fminf(tc, td)), T0);
    const float tmax = fminf(fminf(fmaxf(ta, tb2), fmaxf(tc, td)), T0 + (float)(NS - 1));
    int slo = (int)ceilf(tmin - T0);
    int shi = (int)floorf(tmax - T0);
    slo = max(slo, 0);
    shi = min(shi, NS - 1);

    // band crossing iy2(s) == 130 at s = zf (round-12 verbatim, proven).
    // Misassignment from float fuzz <= ~1e-4 px; guard rows hold REAL image
    // data, so even misassigned boundary samples read exact values.
    float zf = (cy3 - (float)SPLIT) * invy;
    zf = fminf(fmaxf(zf, -1.0e6f), 1.0e6f);
    const int zc  = (int)ceilf(zf);
    const int zfl = (int)floorf(zf);

    int lo_, hi_;
    if (bandT) {
        if (ndy > 0.0f)      { lo_ = slo; hi_ = min(shi, zc - 1); }
        else if (ndy < 0.0f) { lo_ = max(slo, zfl + 1); hi_ = shi; }
        else                 { lo_ = (cy3 < (float)SPLIT) ? slo : 1;
                               hi_ = (cy3 < (float)SPLIT) ? shi : 0; }
    } else {
        if (ndy > 0.0f)      { lo_ = max(slo, zc); hi_ = shi; }
        else if (ndy < 0.0f) { lo_ = slo; hi_ = min(shi, zfl); }
        else                 { lo_ = (cy3 < (float)SPLIT) ? 1 : slo;
                               hi_ = (cy3 < (float)SPLIT) ? 0 : shi; }
    }
    // Band B local row coords: ip_loc = ip - 129.
    const float cy3loc = bandT ? cy3 : (cy3 - (float)BLO_B);
    const float acc = band_loop(tile, lo_, hi_, chunk, dx, ndy, cx3, cy3loc);

    // ---- reduce 2 t-chunks, atomically combine bands ----
    red[tid] = acc;
    __syncthreads();
    if (tid < 512) {
        const float r = (red[tid] + red[tid + 512]) * STEP;
        unsafeAtomicAdd(&out[bv * 512 + tid], r);
    }
}

extern "C" void kernel_launch(void* const* d_in, const int* in_sizes, int n_in,
                              void* d_out, int out_size, void* d_ws, size_t ws_size,
                              hipStream_t stream) {
    const float* x = (const float*)d_in[0];
    float* out = (float*)d_out;
    hipMemsetAsync(out, 0, (size_t)out_size * sizeof(float), stream);
    fanbeam_band2<<<2 * BATCH * VIEWS, 1024, 0, stream>>>(x, out);
}

// Round 14
// 77.096 us; speedup vs baseline: 1.3582x; 1.0385x over previous
//
#include <hip/hip_runtime.h>
#include <hip/hip_fp16.h>
#include <math.h>
#include <string.h>

// ---- geometry constants (match reference) ----
constexpr int   VIEWS = 128;
constexpr int   NDET  = 512;
constexpr int   IMG   = 256;
constexpr int   BATCH = 2;
constexpr float SID_F = 750.0f;
constexpr float SDD_F = 1250.0f;
constexpr float DET_ELT = 1.2f;
constexpr float DET_OFF = 0.0f;
constexpr float STEP  = 1.0f;
constexpr int   NS = 364;                       // ceil(2R)+1, R = 128*sqrt(2)
constexpr float T0 = (float)(750.0 - 181.01933598375618);  // SID - R

// ---- LDS fp16 tile: one batch image with 2-px zero border ----
constexpr int PAD    = 2;
constexpr int TROWS  = IMG + 2 * PAD;           // 260
constexpr int TSTR   = 262;                     // halfs per row
constexpr int TWSTR  = TSTR / 2;                // 131 words per row (odd: bank spread)
constexpr int TWORDS = TROWS * TWSTR;           // 34060 dwords = 136,240 B

typedef _Float16 h2 __attribute__((ext_vector_type(2)));   // native packed arithmetic
using v2h = decltype(__builtin_amdgcn_cvt_pkrtz(0.0f, 0.0f));  // builtin's __fp16 vec

// Block = one (b, view): 1024 threads = 512 detectors x 2 t-chunks.
// Slab test (+-128.75) trims rays to their image-box span; skipped samples are
// provably zero in the reference (all bilinear corners invalid), and the
// tightened bound keeps every LDS access in-tile WITHOUT per-sample clamps.
// Bilinear = 2x ds_read2_b32 + alignbit/perm repack + packed-fp16 lerp.
// [Best measured config: 76.9 us total; structural variants R10/R12/R13
//  (pair-texture, band-split+atomics, 2-blocks/CU) all measured <= this.]
__global__ __launch_bounds__(1024) void fanbeam_lds(const float* __restrict__ img,
                                                    float* __restrict__ out) {
    __shared__ unsigned int tile32[TWORDS];     // fp16 pairs, zero-bordered
    __shared__ float red[1024];
    const int tid = threadIdx.x;
    const int blk = blockIdx.x;                 // = b*VIEWS + v
    const int v = blk & (VIEWS - 1);
    const int b = blk >> 7;

    // ---- border zero-fill (rows 0,1,258,259 fully; words 0,129,130 of rows 2..257)
    for (int k = tid; k < 524 + 768; k += 1024) {
        int w;
        if (k < 524) {
            const int r = k / 131, c = k - r * 131;
            const int row = (r < 2) ? r : 256 + r;      // 0,1,258,259
            w = row * TWSTR + c;
        } else {
            const int kk = k - 524;
            const int row = 2 + kk / 3;
            const int m = kk % 3;
            w = row * TWSTR + ((m == 0) ? 0 : 128 + m);
        }
        tile32[w] = 0u;
    }

    // ---- stage image into LDS as fp16 (interior words 1..128 of rows 2..257)
    const float* __restrict__ src = img + b * IMG * IMG;
    for (int k = tid; k < (IMG * IMG) / 4; k += 1024) {   // 16 iters, float4 coalesced
        const int p = k * 4;
        const int i = p >> 8;
        const int j = p & 255;
        const float4 f = *reinterpret_cast<const float4*>(src + p);
        const unsigned lo = ((unsigned)__half_as_ushort(__float2half(f.y)) << 16)
                          |  (unsigned)__half_as_ushort(__float2half(f.x));
        const unsigned hi = ((unsigned)__half_as_ushort(__float2half(f.w)) << 16)
                          |  (unsigned)__half_as_ushort(__float2half(f.z));
        const int h = (i + PAD) * TSTR + (j + PAD);       // even
        tile32[h >> 1]       = lo;
        tile32[(h >> 1) + 1] = hi;
    }
    __syncthreads();

    // ---- per-ray geometry ----
    const int n     = tid & (NDET - 1);
    const int chunk = tid >> 9;
    const float beta = (float)((double)v * 0.049087385212340517);  // v * pi/64
    const float cb = cosf(beta);
    const float sb = sinf(beta);
    const float u  = ((float)n - 255.5f) * DET_ELT + DET_OFF;
    float dx = fmaf(-u, sb, -SDD_F * cb);
    float dy = fmaf( u, cb, -SDD_F * sb);
    const float inv = rsqrtf(fmaf(dx, dx, dy * dy));
    dx *= inv;
    dy *= inv;
    const float ndy = -dy;
    const float sx = SID_F * cb;
    const float sy = SID_F * sb;
    // biased tile coords: jx2 = t*dx + (sx+127.5+PAD); fold t = T0 + sf:
    const float cx3 = fmaf(T0, dx,  sx + 127.5f + (float)PAD);   // jx2 = sf*dx + cx3
    const float cy3 = fmaf(T0, ndy, 127.5f - sy + (float)PAD);   // iy2 = sf*ndy + cy3

    // ---- slab: t-range where |px|,|py| <= 128.75 ----
    // Outside: all 4 bilinear corners invalid in the reference -> exact 0.
    // Inside: jp,ip in [0,258] -> all LDS reads in-tile, no clamps needed.
    const float invx = 1.0f / dx;
    const float invy = 1.0f / dy;
    const float ta = (-128.75f - sx) * invx, tb = (128.75f - sx) * invx;
    const float tc = (-128.75f - sy) * invy, td = (128.75f - sy) * invy;
    const float txmin = fminf(ta, tb), txmax = fmaxf(ta, tb);
    const float tymin = fminf(tc, td), tymax = fmaxf(tc, td);
    const float tmin = fmaxf(fmaxf(txmin, tymin), T0);
    const float tmax = fminf(fminf(txmax, tymax), T0 + (float)(NS - 1));
    int slo = (int)ceilf(tmin - T0);
    int shi = (int)floorf(tmax - T0);
    slo = max(slo, 0);
    shi = min(shi, NS - 1);

    float acc = 0.0f;
    const int start = slo + chunk;
    // exact count: d>=0 -> d/2+1; any d<0 -> 0 (round-8 lesson: truncating
    // div on negative d gave a spurious OOB iteration -> replay divergence)
    const int iters = max(0, (shi - start + 2) / 2);
    float sfv = (float)start;

#pragma unroll 4
    for (int k = 0; k < iters; ++k) {
        const float jx2 = fmaf(sfv, dx, cx3);   // in [0.75, 258.25]
        const float iy2 = fmaf(sfv, ndy, cy3);
        sfv += 2.0f;                            // exact (integer-valued floats)
        const int jp = (int)jx2;                // trunc == floor (positive)
        const int ip = (int)iy2;
        const float fj = jx2 - (float)jp;
        const float fi = iy2 - (float)ip;
        const int w = ip * TWSTR + (jp >> 1);
        const unsigned w0 = tile32[w];
        const unsigned w1 = tile32[w + 1];
        const unsigned w2 = tile32[w + TWSTR];
        const unsigned w3 = tile32[w + TWSTR + 1];
        const unsigned sh = (unsigned)jp << 4;  // alignbit uses shift[4:0]
        const unsigned ptop = __builtin_amdgcn_alignbit(w1, w0, sh);  // (t0,t1)
        const unsigned pbot = __builtin_amdgcn_alignbit(w3, w2, sh);  // (b0,b1)
        // repack: L=(t0,b0), H=(t1,b1)
        const unsigned Lu = __builtin_amdgcn_perm(pbot, ptop, 0x05040100u);
        const unsigned Hu = __builtin_amdgcn_perm(pbot, ptop, 0x07060302u);
        const h2 L = __builtin_bit_cast(h2, Lu);
        const h2 H = __builtin_bit_cast(h2, Hu);
        const h2 fj2 = __builtin_bit_cast(h2, __builtin_amdgcn_cvt_pkrtz(fj, fj));
        const h2 r = fj2 * (H - L) + L;         // v_pk_fma: (top, bot)
#if __has_builtin(__builtin_amdgcn_fdot2)
        const h2 wv = __builtin_bit_cast(h2, __builtin_amdgcn_cvt_pkrtz(1.0f - fi, fi));
        acc = __builtin_amdgcn_fdot2(__builtin_bit_cast(v2h, r),
                                     __builtin_bit_cast(v2h, wv), acc, false);
#else
        const float top = (float)r.x;
        const float bot = (float)r.y;
        acc = fmaf(fi, bot - top, acc + top);
#endif
    }

    red[tid] = acc;
    __syncthreads();
    if (tid < 512) {
        out[blk * 512 + tid] = (red[tid] + red[tid + 512]) * STEP;
    }
}

extern "C" void kernel_launch(void* const* d_in, const int* in_sizes, int n_in,
                              void* d_out, int out_size, void* d_ws, size_t ws_size,
                              hipStream_t stream) {
    const float* x = (const float*)d_in[0];
    float* out = (float*)d_out;
    fanbeam_lds<<<BATCH * VIEWS, 1024, 0, stream>>>(x, out);
}